// Round 1
// baseline (357.683 us; speedup 1.0000x reference)
//
#include <hip/hip_runtime.h>

#define N_TOK 4096
#define DMODEL 1024
#define NEXP 16
#define HDIM 2048
#define CAP 1024

typedef __attribute__((ext_vector_type(8))) short frag8;      // 8 bf16 (4 VGPR) MFMA operand
typedef __attribute__((ext_vector_type(4))) float f32x4;      // MFMA accumulator
typedef __attribute__((ext_vector_type(8))) unsigned short us8;

__device__ __forceinline__ unsigned short f2bf(float x) {
  unsigned u = __builtin_bit_cast(unsigned, x);
  u += 0x7fffu + ((u >> 16) & 1u);           // RNE
  return (unsigned short)(u >> 16);
}

__device__ __forceinline__ void load_lds16(const void* g, void* l) {
  __builtin_amdgcn_global_load_lds((const __attribute__((address_space(1))) void*)g,
                                   (__attribute__((address_space(3))) void*)l, 16, 0, 0);
}

// ---------------- gate: logits -> top2 -> softmax -> slot assignment ----------------
__global__ __launch_bounds__(256) void gate_kernel(
    const float* __restrict__ x, const float* __restrict__ Wg, const float* __restrict__ bg,
    int* __restrict__ cnt, int* __restrict__ tok_of_slot,
    int* __restrict__ a_e, int* __restrict__ a_slot, float* __restrict__ a_gate)
{
  int wid = threadIdx.x >> 6, l = threadIdx.x & 63;
  int n = blockIdx.x * 4 + wid;
  const float* xr = x + (size_t)n * DMODEL;
  float acc[NEXP];
#pragma unroll
  for (int e = 0; e < NEXP; ++e) acc[e] = 0.f;
  for (int i = l; i < DMODEL; i += 64) {
    float xv = xr[i];
    const float4* wr = (const float4*)(Wg + (size_t)i * NEXP);
#pragma unroll
    for (int q = 0; q < 4; ++q) {
      float4 w = wr[q];
      acc[q*4+0] += xv * w.x; acc[q*4+1] += xv * w.y;
      acc[q*4+2] += xv * w.z; acc[q*4+3] += xv * w.w;
    }
  }
#pragma unroll
  for (int e = 0; e < NEXP; ++e) {
    float v = acc[e];
#pragma unroll
    for (int off = 32; off > 0; off >>= 1) v += __shfl_xor(v, off, 64);
    acc[e] = v + bg[e];
  }
  if (l == 0) {
    int i1 = 0; float v1 = acc[0];
#pragma unroll
    for (int e = 1; e < NEXP; ++e) if (acc[e] > v1) { v1 = acc[e]; i1 = e; }
    int i2 = -1; float v2 = -1e30f;
#pragma unroll
    for (int e = 0; e < NEXP; ++e) if (e != i1 && acc[e] > v2) { v2 = acc[e]; i2 = e; }
    float e2 = __expf(v2 - v1);
    float inv = 1.f / (1.f + e2);
    float g1 = inv, g2 = e2 * inv;
    int s1 = atomicAdd(&cnt[i1], 1);
    if (s1 < CAP) tok_of_slot[i1*CAP + s1] = n; else s1 = CAP;
    int s2 = atomicAdd(&cnt[i2], 1);
    if (s2 < CAP) tok_of_slot[i2*CAP + s2] = n; else s2 = CAP;
    a_e[n*2] = i1;   a_slot[n*2] = s1;   a_gate[n*2] = g1;
    a_e[n*2+1] = i2; a_slot[n*2+1] = s2; a_gate[n*2+1] = g2;
  }
}

// ---------------- gather: x rows -> bf16 blocked+swizzled A-layout [e][rt][kt][128][64] ----------------
__global__ __launch_bounds__(256) void gather_kernel(
    const float* __restrict__ x, const int* __restrict__ cnt,
    const int* __restrict__ tok_of_slot, unsigned short* __restrict__ Xe)
{
  int rid = blockIdx.x * 2 + (threadIdx.x >> 7);
  int tl = threadIdx.x & 127;
  int e = rid >> 10, slot = rid & (CAP - 1);
  int c = cnt[e]; if (c > CAP) c = CAP;
  if (slot >= c) return;
  int tok = tok_of_slot[rid];
  const float4* xs = (const float4*)(x + (size_t)tok * DMODEL + tl * 8);
  float4 u = xs[0], v = xs[1];
  us8 p;
  p[0]=f2bf(u.x); p[1]=f2bf(u.y); p[2]=f2bf(u.z); p[3]=f2bf(u.w);
  p[4]=f2bf(v.x); p[5]=f2bf(v.y); p[6]=f2bf(v.z); p[7]=f2bf(v.w);
  int kt = tl >> 3, s = tl & 7;
  int row = slot & 127, rt = slot >> 7;
  size_t off = ((size_t)((e*8 + rt)*16 + kt)) * 8192 + (size_t)row*64 + ((s ^ (row & 7)) << 3);
  *(us8*)&Xe[off] = p;
}

// ---------------- prepack: src f32 [E][R][C] -> dst bf16 blocked logical [C][R] ----------------
// out blocks: rt over C/128, kt over R/64; within block: row=c%128, slot s=(r%64)/8, swizzle s^(row&7)
__global__ __launch_bounds__(256) void prepack_kernel(
    const float* __restrict__ src, unsigned short* __restrict__ dst, int R, int C)
{
  __shared__ float tr[64 * 133];
  int nrt = C >> 7, nkt = R >> 6;
  int bid = blockIdx.x;
  int e = bid / (nrt * nkt), rem = bid % (nrt * nkt);
  int rt = rem / nkt, kt = rem % nkt;
  int t = threadIdx.x;
  int r0 = kt * 64, c0 = rt * 128;
  const float* sp = src + ((size_t)e * R + r0) * C + c0;
#pragma unroll
  for (int i = 0; i < 8; ++i) {
    int row = i * 8 + (t >> 5), col = (t & 31) * 4;
    float4 v = *(const float4*)(sp + (size_t)row * C + col);
    float* d = &tr[row * 133 + col];
    d[0] = v.x; d[1] = v.y; d[2] = v.z; d[3] = v.w;
  }
  __syncthreads();
  size_t obase = ((size_t)(e * nrt + rt) * nkt + kt) * 8192;
#pragma unroll
  for (int q = 0; q < 4; ++q) {
    int chunk = q * 256 + t;
    int orow = chunk >> 3, sl = chunk & 7;
    us8 p;
#pragma unroll
    for (int j = 0; j < 8; ++j) p[j] = f2bf(tr[(sl*8 + j)*133 + orow]);
    *(us8*)&dst[obase + (size_t)orow*64 + ((sl ^ (orow & 7)) << 3)] = p;
  }
}

// ---------------- grouped GEMM: C[M=slots][N] = A[M][K] * B^T-blocks + bias, opt gelu ----------------
// A,B stored as pre-swizzled 16KB LDS-image blocks; staging = linear global_load_lds
template<int KT, int NT, bool GELU, bool OUT_BLOCKED>
__global__ __launch_bounds__(256) void gemm_kernel(
    const unsigned short* __restrict__ A, const unsigned short* __restrict__ B,
    void* __restrict__ OutP, const float* __restrict__ bias, const int* __restrict__ cnt)
{
  __shared__ __align__(16) unsigned short smem[16384];  // A tile 16KB | B tile 16KB
  constexpr int MT = 8;
  int bid = blockIdx.x;
  int e = bid / (MT * NT), rem = bid % (MT * NT);
  int mt = rem / NT, nt = rem % NT;
  int mcnt = cnt[e]; if (mcnt > CAP) mcnt = CAP;
  if (mt * 128 >= mcnt) return;
  int tid = threadIdx.x, l = tid & 63, wid = tid >> 6;
  int wm = wid >> 1, wn = wid & 1;
  int rA = l & 15, g = l >> 4, r7 = rA & 7;
  const unsigned short* Ab = A + (size_t)(e * MT + mt) * KT * 8192;
  const unsigned short* Bb = B + (size_t)(e * NT + nt) * KT * 8192;
  f32x4 acc[4][4] = {};
  int sw0 = (g ^ r7) << 3;          // kh=0 slot offset (ushorts)
  int sw1 = ((g + 4) ^ r7) << 3;    // kh=1
  int baseA = (wm * 64 + rA) * 64;
  int baseB = 8192 + (wn * 64 + rA) * 64;

  for (int kt = 0; kt < KT; ++kt) {
    __syncthreads();                               // prior reads done
    const unsigned short* As = Ab + (size_t)kt * 8192;
    const unsigned short* Bs = Bb + (size_t)kt * 8192;
#pragma unroll
    for (int i = 0; i < 4; ++i) {
      int chunk = wid * 4 + i;                     // 16 x 1KB chunks each
      load_lds16(As + chunk * 512 + l * 8, &smem[chunk * 512]);
      load_lds16(Bs + chunk * 512 + l * 8, &smem[8192 + chunk * 512]);
    }
    __syncthreads();                               // barrier drains vmcnt
    frag8 bfr[4][2];
#pragma unroll
    for (int n16 = 0; n16 < 4; ++n16) {
      bfr[n16][0] = *(const frag8*)&smem[baseB + n16 * 1024 + sw0];
      bfr[n16][1] = *(const frag8*)&smem[baseB + n16 * 1024 + sw1];
    }
#pragma unroll
    for (int m16 = 0; m16 < 4; ++m16) {
      frag8 a0 = *(const frag8*)&smem[baseA + m16 * 1024 + sw0];
      frag8 a1 = *(const frag8*)&smem[baseA + m16 * 1024 + sw1];
#pragma unroll
      for (int n16 = 0; n16 < 4; ++n16) {
        acc[m16][n16] = __builtin_amdgcn_mfma_f32_16x16x32_bf16(a0, bfr[n16][0], acc[m16][n16], 0, 0, 0);
        acc[m16][n16] = __builtin_amdgcn_mfma_f32_16x16x32_bf16(a1, bfr[n16][1], acc[m16][n16], 0, 0, 0);
      }
    }
  }

  float bv[4];
#pragma unroll
  for (int n16 = 0; n16 < 4; ++n16)
    bv[n16] = bias[e * (NT * 128) + nt * 128 + wn * 64 + n16 * 16 + rA];

  if (OUT_BLOCKED) {
    __syncthreads();                               // done with tile reads
    unsigned short* wbuf = &smem[wid * 4096];      // per-wave 64x64 bf16 bounce
#pragma unroll
    for (int m16 = 0; m16 < 4; ++m16)
#pragma unroll
      for (int n16 = 0; n16 < 4; ++n16)
#pragma unroll
        for (int rr = 0; rr < 4; ++rr) {
          float xv = acc[m16][n16][rr] + bv[n16];
          if (GELU) {
            float u = 0.7978845608028654f * (xv + 0.044715f * xv * xv * xv);
            xv = 0.5f * xv * (1.f + tanhf(u));
          }
          int row = m16 * 16 + g * 4 + rr;
          int col = n16 * 16 + rA;
          wbuf[row * 64 + (((col >> 3) ^ (row & 7)) << 3) + (col & 7)] = f2bf(xv);
        }
    unsigned short* Out = (unsigned short*)OutP;   // blocked [e][mt][kt2=nt*2+wn][128][64]
    size_t ob = ((size_t)(e * 8 + mt) * 32 + nt * 2 + wn) * 8192;
#pragma unroll
    for (int it = 0; it < 8; ++it) {
      int row = it * 8 + (l >> 3), p = l & 7;      // phys slot == out phys slot (XORs cancel)
      us8 v = *(const us8*)&wbuf[row * 64 + (p << 3)];
      *(us8*)&Out[ob + (size_t)(wm * 64 + row) * 64 + (p << 3)] = v;
    }
  } else {
    float* Out = (float*)OutP;                     // linear f32 [e][CAP][NT*128]
#pragma unroll
    for (int m16 = 0; m16 < 4; ++m16)
#pragma unroll
      for (int n16 = 0; n16 < 4; ++n16) {
        int col = nt * 128 + wn * 64 + n16 * 16 + rA;
#pragma unroll
        for (int rr = 0; rr < 4; ++rr) {
          int grow = mt * 128 + wm * 64 + m16 * 16 + g * 4 + rr;
          Out[(size_t)(e * CAP + grow) * (NT * 128) + col] = acc[m16][n16][rr] + bv[n16];
        }
      }
  }
}

// ---------------- combine: out[n] = g0*ye[e0][s0] + g1*ye[e1][s1] ----------------
__global__ __launch_bounds__(256) void combine_kernel(
    const float* __restrict__ ye, const int* __restrict__ a_e, const int* __restrict__ a_slot,
    const float* __restrict__ a_gate, float* __restrict__ out)
{
  int n = blockIdx.x, t = threadIdx.x;
  int e0 = a_e[n*2], e1 = a_e[n*2+1];
  int s0 = a_slot[n*2], s1 = a_slot[n*2+1];
  float g0 = a_gate[n*2], g1 = a_gate[n*2+1];
  float rx = 0.f, ry = 0.f, rz = 0.f, rw = 0.f;
  if (s0 < CAP) {
    float4 v = *(const float4*)&ye[(size_t)(e0*CAP + s0)*DMODEL + t*4];
    rx += g0*v.x; ry += g0*v.y; rz += g0*v.z; rw += g0*v.w;
  }
  if (s1 < CAP) {
    float4 v = *(const float4*)&ye[(size_t)(e1*CAP + s1)*DMODEL + t*4];
    rx += g1*v.x; ry += g1*v.y; rz += g1*v.z; rw += g1*v.w;
  }
  float4 o; o.x = rx; o.y = ry; o.z = rz; o.w = rw;
  *(float4*)&out[(size_t)n*DMODEL + t*4] = o;
}

extern "C" void kernel_launch(void* const* d_in, const int* in_sizes, int n_in,
                              void* d_out, int out_size, void* d_ws, size_t ws_size,
                              hipStream_t stream) {
  const float* x  = (const float*)d_in[0];
  const float* Wg = (const float*)d_in[1];
  const float* bg = (const float*)d_in[2];
  const float* W1 = (const float*)d_in[3];
  const float* b1 = (const float*)d_in[4];
  const float* W2 = (const float*)d_in[5];
  const float* b2 = (const float*)d_in[6];
  float* out = (float*)d_out;
  char* ws = (char*)d_ws;

  // workspace layout (ye overlays W1T: W1T dead after gemm1) — total ~235MB
  unsigned short* W1T = (unsigned short*)(ws);                 // 67,108,864 B
  unsigned short* W2T = (unsigned short*)(ws + 67108864);      // 67,108,864 B
  unsigned short* Xe  = (unsigned short*)(ws + 134217728);     // 33,554,432 B
  unsigned short* hB  = (unsigned short*)(ws + 167772160);     // 67,108,864 B
  float* ye           = (float*)(ws);                          // 67,108,864 B (overlay)
  int* cnt            = (int*)(ws + 234881024);                // 64 B
  int* tok            = (int*)(ws + 234881088);                // 65,536 B
  int* a_e            = (int*)(ws + 234946624);                // 32,768 B
  int* a_slot         = (int*)(ws + 234979392);                // 32,768 B
  float* a_gate       = (float*)(ws + 235012160);              // 32,768 B

  hipMemsetAsync(cnt, 0, 64, stream);
  gate_kernel<<<1024, 256, 0, stream>>>(x, Wg, bg, cnt, tok, a_e, a_slot, a_gate);
  gather_kernel<<<8192, 256, 0, stream>>>(x, cnt, tok, Xe);
  prepack_kernel<<<4096, 256, 0, stream>>>(W1, W1T, DMODEL, HDIM);   // W1T logical [H][D]
  prepack_kernel<<<4096, 256, 0, stream>>>(W2, W2T, HDIM, DMODEL);   // W2T logical [D][H]
  gemm_kernel<16, 16, true,  true ><<<2048, 256, 0, stream>>>(Xe, W1T, (void*)hB, b1, cnt);
  gemm_kernel<32, 8,  false, false><<<1024, 256, 0, stream>>>(hB, W2T, (void*)ye, b2, cnt);
  combine_kernel<<<4096, 256, 0, stream>>>(ye, a_e, a_slot, a_gate, out);
}

// Round 2
// 291.529 us; speedup vs baseline: 1.2269x; 1.2269x over previous
//
#include <hip/hip_runtime.h>

#define N_TOK 4096
#define DMODEL 1024
#define NEXP 16
#define HDIM 2048
#define CAP 1024

typedef __attribute__((ext_vector_type(8))) short frag8;      // 8 bf16 (4 VGPR) MFMA operand
typedef __attribute__((ext_vector_type(4))) float f32x4;      // MFMA accumulator
typedef __attribute__((ext_vector_type(8))) unsigned short us8;

__device__ __forceinline__ unsigned short f2bf(float x) {
  unsigned u = __builtin_bit_cast(unsigned, x);
  u += 0x7fffu + ((u >> 16) & 1u);           // RNE
  return (unsigned short)(u >> 16);
}

__device__ __forceinline__ void load_lds16(const void* g, void* l) {
  __builtin_amdgcn_global_load_lds((const __attribute__((address_space(1))) void*)g,
                                   (__attribute__((address_space(3))) void*)l, 16, 0, 0);
}

// ---------------- gate phase 1: logits -> top2 -> softmax (NO atomics) ----------------
__global__ __launch_bounds__(256) void gate_logits_kernel(
    const float* __restrict__ x, const float* __restrict__ Wg, const float* __restrict__ bg,
    int* __restrict__ a_e, float* __restrict__ a_gate)
{
  int wid = threadIdx.x >> 6, l = threadIdx.x & 63;
  int n = blockIdx.x * 4 + wid;
  const float* xr = x + (size_t)n * DMODEL;
  float acc[NEXP];
#pragma unroll
  for (int e = 0; e < NEXP; ++e) acc[e] = 0.f;
#pragma unroll
  for (int q = 0; q < 4; ++q) {
    float4 xv = *(const float4*)(xr + q * 256 + l * 4);
    const float* wr = Wg + (size_t)(q * 256 + l * 4) * NEXP;
#pragma unroll
    for (int j = 0; j < 4; ++j) {
      float xs = j == 0 ? xv.x : j == 1 ? xv.y : j == 2 ? xv.z : xv.w;
      const float4* w4 = (const float4*)(wr + j * NEXP);
#pragma unroll
      for (int qq = 0; qq < 4; ++qq) {
        float4 w = w4[qq];
        acc[qq*4+0] += xs * w.x; acc[qq*4+1] += xs * w.y;
        acc[qq*4+2] += xs * w.z; acc[qq*4+3] += xs * w.w;
      }
    }
  }
#pragma unroll
  for (int e = 0; e < NEXP; ++e) {
    float v = acc[e];
#pragma unroll
    for (int off = 32; off > 0; off >>= 1) v += __shfl_xor(v, off, 64);
    acc[e] = v + bg[e];
  }
  if (l == 0) {
    int i1 = 0; float v1 = acc[0];
#pragma unroll
    for (int e = 1; e < NEXP; ++e) if (acc[e] > v1) { v1 = acc[e]; i1 = e; }
    int i2 = -1; float v2 = -1e30f;
#pragma unroll
    for (int e = 0; e < NEXP; ++e) if (e != i1 && acc[e] > v2) { v2 = acc[e]; i2 = e; }
    float e2 = __expf(v2 - v1);
    float inv = 1.f / (1.f + e2);
    a_e[n*2] = i1;   a_gate[n*2] = inv;
    a_e[n*2+1] = i2; a_gate[n*2+1] = e2 * inv;
  }
}

// ---------------- gate phase 2: per-expert slot assignment via LDS counter ----------------
__global__ __launch_bounds__(256) void assign_kernel(
    const int* __restrict__ a_e, int* __restrict__ a_slot,
    int* __restrict__ tok_of_slot, int* __restrict__ cnt)
{
  __shared__ int c;
  if (threadIdx.x == 0) c = 0;
  __syncthreads();
  int eid = blockIdx.x;
  for (int j = threadIdx.x; j < N_TOK * 2; j += 256) {
    if (a_e[j] == eid) {
      int p = atomicAdd(&c, 1);
      a_slot[j] = p;
      if (p < CAP) tok_of_slot[eid * CAP + p] = j >> 1;
    }
  }
  __syncthreads();
  if (threadIdx.x == 0) cnt[eid] = c;
}

// ---------------- gather: x rows -> bf16 blocked+swizzled A-layout [e][rt][kt][128][64] ----------------
__global__ __launch_bounds__(256) void gather_kernel(
    const float* __restrict__ x, const int* __restrict__ cnt,
    const int* __restrict__ tok_of_slot, unsigned short* __restrict__ Xe)
{
  int rid = blockIdx.x * 2 + (threadIdx.x >> 7);
  int tl = threadIdx.x & 127;
  int e = rid >> 10, slot = rid & (CAP - 1);
  int c = cnt[e]; if (c > CAP) c = CAP;
  if (slot >= c) return;
  int tok = tok_of_slot[rid];
  const float4* xs = (const float4*)(x + (size_t)tok * DMODEL + tl * 8);
  float4 u = xs[0], v = xs[1];
  us8 p;
  p[0]=f2bf(u.x); p[1]=f2bf(u.y); p[2]=f2bf(u.z); p[3]=f2bf(u.w);
  p[4]=f2bf(v.x); p[5]=f2bf(v.y); p[6]=f2bf(v.z); p[7]=f2bf(v.w);
  int kt = tl >> 3, s = tl & 7;
  int row = slot & 127, rt = slot >> 7;
  size_t off = ((size_t)((e*8 + rt)*16 + kt)) * 8192 + (size_t)row*64 + ((s ^ (row & 7)) << 3);
  *(us8*)&Xe[off] = p;
}

// ---------------- prepack: src f32 [E][R][C] -> dst bf16 blocked logical [C][R] ----------------
__global__ __launch_bounds__(256) void prepack_kernel(
    const float* __restrict__ src, unsigned short* __restrict__ dst, int R, int C)
{
  __shared__ float tr[64 * 133];
  int nrt = C >> 7, nkt = R >> 6;
  int bid = blockIdx.x;
  int e = bid / (nrt * nkt), rem = bid % (nrt * nkt);
  int rt = rem / nkt, kt = rem % nkt;
  int t = threadIdx.x;
  int r0 = kt * 64, c0 = rt * 128;
  const float* sp = src + ((size_t)e * R + r0) * C + c0;
#pragma unroll
  for (int i = 0; i < 8; ++i) {
    int row = i * 8 + (t >> 5), col = (t & 31) * 4;
    float4 v = *(const float4*)(sp + (size_t)row * C + col);
    float* d = &tr[row * 133 + col];
    d[0] = v.x; d[1] = v.y; d[2] = v.z; d[3] = v.w;
  }
  __syncthreads();
  size_t obase = ((size_t)(e * nrt + rt) * nkt + kt) * 8192;
#pragma unroll
  for (int q = 0; q < 4; ++q) {
    int chunk = q * 256 + t;
    int orow = chunk >> 3, sl = chunk & 7;
    us8 p;
#pragma unroll
    for (int j = 0; j < 8; ++j) p[j] = f2bf(tr[(sl*8 + j)*133 + orow]);
    *(us8*)&dst[obase + (size_t)orow*64 + ((sl ^ (orow & 7)) << 3)] = p;
  }
}

// ---------------- grouped GEMM: C[M=slots][N] = A[M][K] * B^T-blocks + bias, opt gelu ----------------
template<int KT, int NT, bool GELU, bool OUT_BLOCKED>
__global__ __launch_bounds__(256) void gemm_kernel(
    const unsigned short* __restrict__ A, const unsigned short* __restrict__ B,
    void* __restrict__ OutP, const float* __restrict__ bias, const int* __restrict__ cnt)
{
  __shared__ __align__(16) unsigned short smem[16384];  // A tile 16KB | B tile 16KB
  constexpr int MT = 8;
  int bid = blockIdx.x;
  int e = bid / (MT * NT), rem = bid % (MT * NT);
  int mt = rem / NT, nt = rem % NT;
  int mcnt = cnt[e]; if (mcnt > CAP) mcnt = CAP;
  if (mt * 128 >= mcnt) return;
  int tid = threadIdx.x, l = tid & 63, wid = tid >> 6;
  int wm = wid >> 1, wn = wid & 1;
  int rA = l & 15, g = l >> 4, r7 = rA & 7;
  const unsigned short* Ab = A + (size_t)(e * MT + mt) * KT * 8192;
  const unsigned short* Bb = B + (size_t)(e * NT + nt) * KT * 8192;
  f32x4 acc[4][4] = {};
  int sw0 = (g ^ r7) << 3;
  int sw1 = ((g + 4) ^ r7) << 3;
  int baseA = (wm * 64 + rA) * 64;
  int baseB = 8192 + (wn * 64 + rA) * 64;

  for (int kt = 0; kt < KT; ++kt) {
    __syncthreads();
    const unsigned short* As = Ab + (size_t)kt * 8192;
    const unsigned short* Bs = Bb + (size_t)kt * 8192;
#pragma unroll
    for (int i = 0; i < 4; ++i) {
      int chunk = wid * 4 + i;
      load_lds16(As + chunk * 512 + l * 8, &smem[chunk * 512]);
      load_lds16(Bs + chunk * 512 + l * 8, &smem[8192 + chunk * 512]);
    }
    __syncthreads();
    frag8 bfr[4][2];
#pragma unroll
    for (int n16 = 0; n16 < 4; ++n16) {
      bfr[n16][0] = *(const frag8*)&smem[baseB + n16 * 1024 + sw0];
      bfr[n16][1] = *(const frag8*)&smem[baseB + n16 * 1024 + sw1];
    }
#pragma unroll
    for (int m16 = 0; m16 < 4; ++m16) {
      frag8 a0 = *(const frag8*)&smem[baseA + m16 * 1024 + sw0];
      frag8 a1 = *(const frag8*)&smem[baseA + m16 * 1024 + sw1];
#pragma unroll
      for (int n16 = 0; n16 < 4; ++n16) {
        acc[m16][n16] = __builtin_amdgcn_mfma_f32_16x16x32_bf16(a0, bfr[n16][0], acc[m16][n16], 0, 0, 0);
        acc[m16][n16] = __builtin_amdgcn_mfma_f32_16x16x32_bf16(a1, bfr[n16][1], acc[m16][n16], 0, 0, 0);
      }
    }
  }

  float bv[4];
#pragma unroll
  for (int n16 = 0; n16 < 4; ++n16)
    bv[n16] = bias[e * (NT * 128) + nt * 128 + wn * 64 + n16 * 16 + rA];

  if (OUT_BLOCKED) {
    __syncthreads();
    unsigned short* wbuf = &smem[wid * 4096];
#pragma unroll
    for (int m16 = 0; m16 < 4; ++m16)
#pragma unroll
      for (int n16 = 0; n16 < 4; ++n16)
#pragma unroll
        for (int rr = 0; rr < 4; ++rr) {
          float xv = acc[m16][n16][rr] + bv[n16];
          if (GELU) {
            float u = 0.7978845608028654f * (xv + 0.044715f * xv * xv * xv);
            xv = 0.5f * xv * (1.f + tanhf(u));
          }
          int row = m16 * 16 + g * 4 + rr;
          int col = n16 * 16 + rA;
          wbuf[row * 64 + (((col >> 3) ^ (row & 7)) << 3) + (col & 7)] = f2bf(xv);
        }
    unsigned short* Out = (unsigned short*)OutP;   // blocked [e][mt][kt2=nt*2+wn][128][64]
    size_t ob = ((size_t)(e * 8 + mt) * 32 + nt * 2 + wn) * 8192;
#pragma unroll
    for (int it = 0; it < 8; ++it) {
      int row = it * 8 + (l >> 3), p = l & 7;
      us8 v = *(const us8*)&wbuf[row * 64 + (p << 3)];
      *(us8*)&Out[ob + (size_t)(wm * 64 + row) * 64 + (p << 3)] = v;
    }
  } else {
    float* Out = (float*)OutP;                     // linear f32 [e][CAP][NT*128]
#pragma unroll
    for (int m16 = 0; m16 < 4; ++m16)
#pragma unroll
      for (int n16 = 0; n16 < 4; ++n16) {
        int col = nt * 128 + wn * 64 + n16 * 16 + rA;
#pragma unroll
        for (int rr = 0; rr < 4; ++rr) {
          int grow = mt * 128 + wm * 64 + m16 * 16 + g * 4 + rr;
          Out[(size_t)(e * CAP + grow) * (NT * 128) + col] = acc[m16][n16][rr] + bv[n16];
        }
      }
  }
}

// ---------------- combine: out[n] = g0*ye[e0][s0] + g1*ye[e1][s1] ----------------
__global__ __launch_bounds__(256) void combine_kernel(
    const float* __restrict__ ye, const int* __restrict__ a_e, const int* __restrict__ a_slot,
    const float* __restrict__ a_gate, float* __restrict__ out)
{
  int n = blockIdx.x, t = threadIdx.x;
  int e0 = a_e[n*2], e1 = a_e[n*2+1];
  int s0 = a_slot[n*2], s1 = a_slot[n*2+1];
  float g0 = a_gate[n*2], g1 = a_gate[n*2+1];
  float rx = 0.f, ry = 0.f, rz = 0.f, rw = 0.f;
  if (s0 < CAP) {
    float4 v = *(const float4*)&ye[(size_t)(e0*CAP + s0)*DMODEL + t*4];
    rx += g0*v.x; ry += g0*v.y; rz += g0*v.z; rw += g0*v.w;
  }
  if (s1 < CAP) {
    float4 v = *(const float4*)&ye[(size_t)(e1*CAP + s1)*DMODEL + t*4];
    rx += g1*v.x; ry += g1*v.y; rz += g1*v.z; rw += g1*v.w;
  }
  float4 o; o.x = rx; o.y = ry; o.z = rz; o.w = rw;
  *(float4*)&out[(size_t)n*DMODEL + t*4] = o;
}

extern "C" void kernel_launch(void* const* d_in, const int* in_sizes, int n_in,
                              void* d_out, int out_size, void* d_ws, size_t ws_size,
                              hipStream_t stream) {
  const float* x  = (const float*)d_in[0];
  const float* Wg = (const float*)d_in[1];
  const float* bg = (const float*)d_in[2];
  const float* W1 = (const float*)d_in[3];
  const float* b1 = (const float*)d_in[4];
  const float* W2 = (const float*)d_in[5];
  const float* b2 = (const float*)d_in[6];
  float* out = (float*)d_out;
  char* ws = (char*)d_ws;

  // workspace layout (ye overlays W1T: W1T dead after gemm1) — total ~235MB
  unsigned short* W1T = (unsigned short*)(ws);                 // 67,108,864 B
  unsigned short* W2T = (unsigned short*)(ws + 67108864);      // 67,108,864 B
  unsigned short* Xe  = (unsigned short*)(ws + 134217728);     // 33,554,432 B
  unsigned short* hB  = (unsigned short*)(ws + 167772160);     // 67,108,864 B
  float* ye           = (float*)(ws);                          // 67,108,864 B (overlay)
  int* cnt            = (int*)(ws + 234881024);                // 64 B
  int* tok            = (int*)(ws + 234881088);                // 65,536 B
  int* a_e            = (int*)(ws + 234946624);                // 32,768 B
  int* a_slot         = (int*)(ws + 234979392);                // 32,768 B
  float* a_gate       = (float*)(ws + 235012160);              // 32,768 B

  gate_logits_kernel<<<1024, 256, 0, stream>>>(x, Wg, bg, a_e, a_gate);
  assign_kernel<<<16, 256, 0, stream>>>(a_e, a_slot, tok, cnt);
  gather_kernel<<<8192, 256, 0, stream>>>(x, cnt, tok, Xe);
  prepack_kernel<<<4096, 256, 0, stream>>>(W1, W1T, DMODEL, HDIM);   // W1T logical [H][D]
  prepack_kernel<<<4096, 256, 0, stream>>>(W2, W2T, HDIM, DMODEL);   // W2T logical [D][H]
  gemm_kernel<16, 16, true,  true ><<<2048, 256, 0, stream>>>(Xe, W1T, (void*)hB, b1, cnt);
  gemm_kernel<32, 8,  false, false><<<1024, 256, 0, stream>>>(hB, W2T, (void*)ye, b2, cnt);
  combine_kernel<<<4096, 256, 0, stream>>>(ye, a_e, a_slot, a_gate, out);
}